// Round 14
// baseline (70.858 us; speedup 1.0000x reference)
//
#include <hip/hip_runtime.h>

typedef _Float16 f16;
typedef __attribute__((ext_vector_type(8))) _Float16 f16x8;
typedef __attribute__((ext_vector_type(4))) _Float16 f16x4;
typedef __attribute__((ext_vector_type(4))) float f32x4;

#define MFMA16(a, b, c) __builtin_amdgcn_mfma_f32_16x16x32_f16(a, b, c, 0, 0, 0)

#define B_N 16384
#define E_N 9
#define TILE 32
#define NTILE_MAX 520  // = 8*65, bijective XCD swizzle
#define THREADS 1024   // 16 waves

#define D_IN 512
#define D_H1 512
#define D_H2 256
#define D_H3 128
#define D_A 16

// Weight image v3: per expert 16 streams of 1KB B-fragment records.
// Stream s: byte offset (e*832 + (s<8 ? s*56 : 448+(s-8)*48)) KB.
// Streams 0..7: 56 records (L1 32, L2 16, L3 8); streams 8..15: 48 (no L3).
// Record r, lane l (lg=l>>4, ln=l&15) holds W[n][k..k+7]:
//   r<32  (L1/W1): n = s*32 + (r&1)*16 + ln, k = (r>>1)*32 + lg*8
//   32..47(L2/W2): n = s*16 + ln,            k = (r-32)*32 + lg*8
//   48..55(L3/W3): n = s*16 + ln,            k = (r-48)*32 + lg*8
// L4: plain [16n][128k] per expert (4KB) at O4B. Total bytes unchanged.
#define O4B 7667712    // 9 * 832 KB
#define WPL_BYTES 7704576
#define WSLOTS (WPL_BYTES / 16)

#define IDX_OFF 64
#define WP_OFF 131584

// LDS 48KB: x/h1 [32][1024B] at 0 (h1 overwrites x, acc-carried);
// h2 [32][512B] at 32K; h3 [32][256B] at 0 (after h1 dead).
#define H2_OFF 32768
#define LDS_BYTES 49152   // x2 blocks = 96KB; 32 waves/CU = HW max

// ---------------- bucketing ----------------

__global__ void k_bucket(const int* __restrict__ pos, int* __restrict__ hdr,
                         int* __restrict__ idx) {
  __shared__ int cnt[E_N], cur[E_N];
  __shared__ int flag_s;
  const int t = threadIdx.x;  // 1024
  if (t < E_N) cnt[t] = 0;
  if (t == 0) {
    int nz = 0;
    for (int i = 0; i < 64; ++i) nz |= pos[2 * i + 1];
    flag_s = (nz == 0) ? 1 : 0;  // int64 layout if all high words zero
  }
  __syncthreads();
  const bool f64 = flag_s != 0;
  int e[16];
#pragma unroll
  for (int k = 0; k < 16; ++k) {
    int i = k * 1024 + t;
    long long v = f64 ? ((const long long*)pos)[i] : (long long)pos[i];
    v = v < 0 ? 0 : (v > 8 ? 8 : v);
    e[k] = (int)v;
    atomicAdd(&cnt[e[k]], 1);
  }
  __syncthreads();
  if (t == 0) {
    int acc = 0;
    for (int ee = 0; ee < E_N; ++ee) { cur[ee] = acc; acc += cnt[ee]; }
  }
  if (t < E_N) hdr[8 + t] = cnt[t];
  __syncthreads();
#pragma unroll
  for (int k = 0; k < 16; ++k) {
    int i = k * 1024 + t;
    int slot = atomicAdd(&cur[e[k]], 1);
    idx[slot] = i;
  }
}

// ---------------- weight convert fp32 -> 16-stream fragment image ----------------

__global__ void k_wcvt(const float* __restrict__ W1, const float* __restrict__ W2,
                       const float* __restrict__ W3, const float* __restrict__ W4,
                       char* __restrict__ wp) {
  int slot = blockIdx.x * 256 + threadIdx.x;
  if (slot >= WSLOTS) return;
  long addr = (long)slot << 4;
  int lane = (int)((addr >> 4) & 63);
  int lg = lane >> 4, ln = lane & 15;
  const float* src;
  if (addr < O4B) {
    int rec = (int)(addr >> 10);   // global record index, 832 per expert
    int e = rec / 832;
    int q = rec - e * 832;
    int s, r;
    if (q < 448) { s = q / 56; r = q - s * 56; }
    else { int q2 = q - 448; s = 8 + q2 / 48; r = q2 - (s - 8) * 48; }
    if (r < 32) {
      int n = s * 32 + (r & 1) * 16 + ln;
      int k = (r >> 1) * 32 + lg * 8;
      src = W1 + ((long)e * D_H1 + n) * D_IN + k;
    } else if (r < 48) {
      int n = s * 16 + ln;
      int k = (r - 32) * 32 + lg * 8;
      src = W2 + ((long)e * D_H2 + n) * D_H1 + k;
    } else {
      int n = (s & 7) * 16 + ln;   // s>=8 never consumed; duplicate s&7
      int k = (r - 48) * 32 + lg * 8;
      src = W3 + ((long)e * D_H3 + n) * D_H2 + k;
    }
  } else {
    long rel = addr - O4B;
    int e = (int)(rel >> 12);
    int r2 = (int)(rel & 4095);
    int s = r2 >> 4, n = s >> 4, k16 = s & 15;
    src = W4 + ((long)e * D_A + n) * D_H3 + k16 * 8;
  }
  float4 a = *(const float4*)src;
  float4 b = *(const float4*)(src + 4);
  f16x8 h;
  h[0] = (f16)a.x; h[1] = (f16)a.y; h[2] = (f16)a.z; h[3] = (f16)a.w;
  h[4] = (f16)b.x; h[5] = (f16)b.y; h[6] = (f16)b.z; h[7] = (f16)b.w;
  *(f16x8*)(wp + addr) = h;
}

// ---------------- fused MLP (16 waves, TILE=32) ----------------

__device__ __forceinline__ f16x8 afrag(const char* base, int strideB, int rowoff,
                                       int kbytes, int lane) {
  int m = rowoff + (lane & 15);
  int q = kbytes + ((lane >> 4) * 16);
  return *(const f16x8*)(base + m * strideB + (q ^ ((m & 15) << 4)));
}

__device__ __forceinline__ f16x8 ldfrag(const char* wb, int f, int lane) {
  return *(const f16x8*)(wb + (long)f * 1024 + lane * 16);
}

__launch_bounds__(THREADS, 2)
__global__ void k_mlp(const float* __restrict__ x,
                      const float* __restrict__ b1, const float* __restrict__ b2,
                      const float* __restrict__ b3, const float* __restrict__ b4,
                      const int* __restrict__ hdr, const int* __restrict__ idx,
                      const char* __restrict__ wp, float* __restrict__ out) {
  __shared__ __align__(16) char lds[LDS_BYTES];

  int b = blockIdx.x;
  int bswz = (b & 7) * (NTILE_MAX / 8) + (b >> 3);  // bijective, 520 = 8*65

  const int* counts = hdr + 8;
  int e = -1, tile = 0, base = 0, ne = 0;
  {
    int acc = 0, off = 0;
    for (int ee = 0; ee < E_N; ++ee) {
      int n = counts[ee];
      int nt = (n + TILE - 1) / TILE;
      if (bswz < acc + nt) { e = ee; tile = bswz - acc; ne = n; base = off; break; }
      acc += nt; off += n;
    }
  }
  if (e < 0) return;
  const int rvalid = min(TILE, ne - tile * TILE);
  const int row0 = base + tile * TILE;

  const int t = threadIdx.x;
  const int lane = t & 63;
  const int wid = t >> 6;     // 0..15
  const int lg = lane >> 4;
  const int ln = lane & 15;

  const char* wb = wp + ((long)e * 832 +
                         (wid < 8 ? wid * 56 : 448 + (wid - 8) * 48)) * 1024;
  const char* wpe4 = wp + O4B + (long)e * 4096;

  // depth-4 register queue over this wave's stream
  f16x8 Q[4];
  Q[0] = ldfrag(wb, 0, lane);
  Q[1] = ldfrag(wb, 1, lane);
  Q[2] = ldfrag(wb, 2, lane);
  Q[3] = ldfrag(wb, 3, lane);

  // ---- stage x tile as fp16, XOR-swizzled ----
  const float4* x4 = (const float4*)x;
#pragma unroll
  for (int v8 = 0; v8 < 4; ++v8) {
    int u = v8 * THREADS + t;              // 4096 = 32*128 float4s
    int s = u >> 7, c4 = u & 127;
    float4 v = make_float4(0.f, 0.f, 0.f, 0.f);
    if (s < rvalid) v = x4[(long)idx[row0 + s] * (D_IN / 4) + c4];
    f16x4 h;
    h[0] = (f16)v.x; h[1] = (f16)v.y; h[2] = (f16)v.z; h[3] = (f16)v.w;
    *(f16x4*)(lds + s * 1024 + ((c4 * 8) ^ ((s & 15) << 4))) = h;
  }
  __syncthreads();

  // ---------------- L1: h1[32x512] = x @ W1^T (recs 0..31) ----------------
  f32x4 acc[2][2];
#pragma unroll
  for (int m = 0; m < 2; ++m)
#pragma unroll
    for (int nf = 0; nf < 2; ++nf) acc[m][nf] = (f32x4){0.f, 0.f, 0.f, 0.f};

#pragma unroll
  for (int kk = 0; kk < 16; ++kk) {
    f16x8 A0 = afrag(lds, 1024, 0, kk * 64, lane);
    f16x8 A1 = afrag(lds, 1024, 16, kk * 64, lane);
#pragma unroll
    for (int nf = 0; nf < 2; ++nf) {
      const int r = kk * 2 + nf;
      f16x8 B = Q[r & 3];
      __builtin_amdgcn_s_setprio(1);
      acc[0][nf] = MFMA16(A0, B, acc[0][nf]);
      acc[1][nf] = MFMA16(A1, B, acc[1][nf]);
      __builtin_amdgcn_s_setprio(0);
      Q[r & 3] = ldfrag(wb, r + 4, lane);  // r+4 <= 35: flows into L2 recs
    }
  }
  __syncthreads();  // all x reads done; x region dead (acc carries h1)

  // write h1 = relu(acc+bias) into region 0 (overwrites x)
#pragma unroll
  for (int nf = 0; nf < 2; ++nf) {
    int n = wid * 32 + nf * 16 + ln;
    float bias = b1[e * D_H1 + n];
#pragma unroll
    for (int m = 0; m < 2; ++m)
#pragma unroll
      for (int j = 0; j < 4; ++j) {
        float v = acc[m][nf][j] + bias;
        v = v > 0.f ? v : 0.f;
        int rw = m * 16 + lg * 4 + j;
        *(f16*)(lds + rw * 1024 + ((n * 2) ^ ((rw & 15) << 4))) = (f16)v;
      }
  }
  __syncthreads();

  // ---------------- L2: h2[32x256] = h1 @ W2^T (recs 32..47) ----------------
  {
    f32x4 acc2[2];
    acc2[0] = (f32x4){0.f, 0.f, 0.f, 0.f};
    acc2[1] = (f32x4){0.f, 0.f, 0.f, 0.f};
#pragma unroll
    for (int kk = 0; kk < 16; ++kk) {
      f16x8 A0 = afrag(lds, 1024, 0, kk * 64, lane);
      f16x8 A1 = afrag(lds, 1024, 16, kk * 64, lane);
      const int r = 32 + kk;
      f16x8 B = Q[r & 3];
      __builtin_amdgcn_s_setprio(1);
      acc2[0] = MFMA16(A0, B, acc2[0]);
      acc2[1] = MFMA16(A1, B, acc2[1]);
      __builtin_amdgcn_s_setprio(0);
      Q[r & 3] = ldfrag(wb, r + 4, lane);  // r+4 <= 51 (in-image for all streams)
    }
    // h2 region (32K..48K) disjoint from h1: direct write
    int n = wid * 16 + ln;
    float bias = b2[e * D_H2 + n];
#pragma unroll
    for (int m = 0; m < 2; ++m)
#pragma unroll
      for (int j = 0; j < 4; ++j) {
        float v = acc2[m][j] + bias;
        v = v > 0.f ? v : 0.f;
        int rw = m * 16 + lg * 4 + j;
        *(f16*)(lds + H2_OFF + rw * 512 + ((n * 2) ^ ((rw & 15) << 4))) = (f16)v;
      }
  }
  __syncthreads();

  // ---------------- L3: h3[32x128] = h2 @ W3^T (recs 48..55, waves 0..7) ----------------
  if (wid < 8) {
    f32x4 acc3[2];
    acc3[0] = (f32x4){0.f, 0.f, 0.f, 0.f};
    acc3[1] = (f32x4){0.f, 0.f, 0.f, 0.f};
#pragma unroll
    for (int kk = 0; kk < 8; ++kk) {
      const int r = 48 + kk;
      f16x8 A0 = afrag(lds + H2_OFF, 512, 0, kk * 64, lane);
      f16x8 A1 = afrag(lds + H2_OFF, 512, 16, kk * 64, lane);
      f16x8 B = Q[r & 3];
      __builtin_amdgcn_s_setprio(1);
      acc3[0] = MFMA16(A0, B, acc3[0]);
      acc3[1] = MFMA16(A1, B, acc3[1]);
      __builtin_amdgcn_s_setprio(0);
      if (r + 4 <= 55) Q[r & 3] = ldfrag(wb, r + 4, lane);
    }
    int n = wid * 16 + ln;
    float bias = b3[e * D_H3 + n];
    // h3 [32][256B] at 0 (h1 dead after L2's barrier)
#pragma unroll
    for (int m = 0; m < 2; ++m)
#pragma unroll
      for (int j = 0; j < 4; ++j) {
        float v = acc3[m][j] + bias;
        v = v > 0.f ? v : 0.f;
        int rw = m * 16 + lg * 4 + j;
        *(f16*)(lds + rw * 256 + ((n * 2) ^ ((rw & 15) << 4))) = (f16)v;
      }
  }
  __syncthreads();

  // ---------------- L4 + softmax (waves 0,1; 16 rows each) ----------------
  if (wid < 2) {
    f32x4 a4 = (f32x4){0.f, 0.f, 0.f, 0.f};
#pragma unroll
    for (int kc = 0; kc < 4; ++kc) {
      f16x8 Bv = *(const f16x8*)(wpe4 + ln * 256 + kc * 64 + lg * 16);
      f16x8 Av = afrag(lds, 256, wid * 16, kc * 64, lane);
      a4 = MFMA16(Av, Bv, a4);
    }
    float bias = b4[e * D_A + ln];
#pragma unroll
    for (int j = 0; j < 4; ++j) {
      float v = a4[j] + bias;
      float mx = v;
      for (int msk = 8; msk >= 1; msk >>= 1) mx = fmaxf(mx, __shfl_xor(mx, msk));
      float pe = expf(v - mx);
      float sm = pe;
      for (int msk = 8; msk >= 1; msk >>= 1) sm += __shfl_xor(sm, msk);
      int rl = wid * 16 + lg * 4 + j;
      if (rl < rvalid) out[(long)idx[row0 + rl] * D_A + ln] = pe / sm;
    }
  }
}

// ---------------- host ----------------

extern "C" void kernel_launch(void* const* d_in, const int* in_sizes, int n_in,
                              void* d_out, int out_size, void* d_ws, size_t ws_size,
                              hipStream_t stream) {
  const float* x  = (const float*)d_in[0];
  const int* pos  = (const int*)d_in[1];
  const float* W1 = (const float*)d_in[2];
  const float* b1 = (const float*)d_in[3];
  const float* W2 = (const float*)d_in[4];
  const float* b2 = (const float*)d_in[5];
  const float* W3 = (const float*)d_in[6];
  const float* b3 = (const float*)d_in[7];
  const float* W4 = (const float*)d_in[8];
  const float* b4 = (const float*)d_in[9];
  float* out = (float*)d_out;

  int* hdr = (int*)d_ws;
  int* idx = hdr + IDX_OFF;
  char* wp = (char*)d_ws + WP_OFF;

  hipLaunchKernelGGL(k_bucket, dim3(1), dim3(1024), 0, stream, pos, hdr, idx);
  hipLaunchKernelGGL(k_wcvt, dim3(WSLOTS / 256), dim3(256), 0, stream,
                     W1, W2, W3, W4, wp);
  hipLaunchKernelGGL(k_mlp, dim3(NTILE_MAX), dim3(THREADS), 0, stream,
                     x, b1, b2, b3, b4, hdr, idx, wp, out);
}